// Round 12
// baseline (203.174 us; speedup 1.0000x reference)
//
#include <hip/hip_runtime.h>

typedef unsigned short u16;
typedef unsigned int   u32;
typedef __attribute__((ext_vector_type(8)))  short bf16x8;
typedef __attribute__((ext_vector_type(4)))  float f32x4;
typedef __attribute__((ext_vector_type(2)))  float f32x2;
typedef __attribute__((ext_vector_type(16))) float f32x16;

#define NFEAT  256
#define NBATCH 8192
#define BT     128   // batch tile per iteration (4 waves: 2 o-halves x 2 b-halves)
#define NBT    (NBATCH / BT)   // 64
#define ITERS  8     // bt-iterations per persistent block -> grid 2048

__device__ __forceinline__ u16 f2bf(float f) {
    u32 u = __builtin_bit_cast(u32, f);
    return (u16)((u + 0x7FFFu + ((u >> 16) & 1u)) >> 16);
}
__device__ __forceinline__ u32 cvtpk(float a, float b) {
    u32 r;
    asm("v_cvt_pk_bf16_f32 %0, %1, %2" : "=v"(r) : "v"(a), "v"(b));
    return r;   // lo16 = bf16(a), hi16 = bf16(b), RNE
}
__device__ __forceinline__ f32x4 mfma16(bf16x8 a, bf16x8 b, f32x4 c) {
    return __builtin_amdgcn_mfma_f32_16x16x32_bf16(a, b, c, 0, 0, 0);
}
__device__ __forceinline__ f32x16 mfma32(bf16x8 a, bf16x8 b, f32x16 c) {
    return __builtin_amdgcn_mfma_f32_32x32x16_bf16(a, b, c, 0, 0, 0);
}
__device__ __forceinline__ bf16x8 frag_word0(u32 word0) {
    union { bf16x8 v; u32 w[4]; } u;
    u.w[0] = word0; u.w[1] = 0; u.w[2] = 0; u.w[3] = 0;
    return u.v;
}
// XOR swizzle, 256B rows (R8-proven; R10's rotate variant measured 2x worse)
__device__ __forceinline__ char* swz(char* base, int b, int col2) {
    return base + b * 256 + (col2 ^ ((b & 15) << 4));
}
__device__ __forceinline__ const char* swz(const char* base, int b, int col2) {
    return base + b * 256 + (col2 ^ ((b & 15) << 4));
}

// ---------------------------------------------------------------------------
// prep: w0[f,o] = g_in[f,o] * sign(v_in[f,o,0])
// ---------------------------------------------------------------------------
__global__ void prep_w0(const float* __restrict__ v_in, const float* __restrict__ g_in,
                        u16* __restrict__ w0) {
    int i = blockIdx.x * blockDim.x + threadIdx.x;   // < 32768
    float v = v_in[i];
    float g = g_in[i];
    w0[i] = f2bf(v >= 0.f ? g : -g);
}

// ---------------------------------------------------------------------------
// prep: weight-normalize v_h0/v_h1/v_out rows -> bf16.  One wave per row.
// ---------------------------------------------------------------------------
__global__ void prep_norm(const float* __restrict__ v_h0, const float* __restrict__ g_h0,
                          const float* __restrict__ v_h1, const float* __restrict__ g_h1,
                          const float* __restrict__ v_out, const float* __restrict__ g_out,
                          u16* __restrict__ w1, u16* __restrict__ w2, u16* __restrict__ w3) {
    const int wave = (blockIdx.x * blockDim.x + threadIdx.x) >> 6;
    const int lane = threadIdx.x & 63;
    if (wave < 32768 + 16384) {
        const float* src; u16* dst; float g;
        if (wave < 32768) {
            src = v_h0 + (size_t)wave * 128; dst = w1 + (size_t)wave * 128; g = g_h0[wave];
        } else {
            int r = wave - 32768;
            src = v_h1 + (size_t)r * 128; dst = w2 + (size_t)r * 128; g = g_h1[r];
        }
        f32x2 v = *(const f32x2*)(src + lane * 2);
        float ss = v[0] * v[0] + v[1] * v[1];
        #pragma unroll
        for (int off = 32; off; off >>= 1) ss += __shfl_xor(ss, off);
        float s = g * rsqrtf(ss);
        *(u32*)(dst + lane * 2) = cvtpk(v[0] * s, v[1] * s);
    } else {
        int r = wave - 49152;   // < 4096
        const float* src = v_out + (size_t)r * 64;
        float v = src[lane];
        float ss = v * v;
        #pragma unroll
        for (int off = 32; off; off >>= 1) ss += __shfl_xor(ss, off);
        float s = g_out[r] * rsqrtf(ss);
        w3[(size_t)r * 64 + lane] = f2bf(v * s);
    }
}

// ---------------------------------------------------------------------------
// prep: x_t[f][b] = bf16( tab[b,0,f] * (1 - tab[b,1,f]) )   (64x64 LDS transpose)
// ---------------------------------------------------------------------------
__global__ void prep_x(const float* __restrict__ tab, u16* __restrict__ x_t) {
    __shared__ u16 tile[64][65];
    const int bb = (blockIdx.x % (NBATCH / 64)) * 64;
    const int ff = (blockIdx.x / (NBATCH / 64)) * 64;
    const int tr = threadIdx.x >> 6;    // 0..3
    const int tc = threadIdx.x & 63;
    #pragma unroll
    for (int i = 0; i < 16; i++) {
        int b = bb + tr + i * 4;
        float val  = tab[(size_t)b * 512 + ff + tc];
        float miss = tab[(size_t)b * 512 + 256 + ff + tc];
        tile[tr + i * 4][tc] = f2bf(val * (1.f - miss));
    }
    __syncthreads();
    #pragma unroll
    for (int i = 0; i < 16; i++) {
        int fr = tr + i * 4;
        x_t[(size_t)(ff + fr) * NBATCH + bb + tc] = tile[tc][fr];
    }
}

// ---------------------------------------------------------------------------
// logits[b][j] = bias[j] + sum_f outputs[b][f][j]
// ---------------------------------------------------------------------------
__global__ void reduce_logits(const float* __restrict__ outputs,
                              const float* __restrict__ bias,
                              float* __restrict__ logits) {
    const int b = blockIdx.x * 4 + (threadIdx.x >> 6);
    const int lane = threadIdx.x & 63;
    const int j4 = lane & 3;     // output quad
    const int fo = lane >> 2;    // feature offset 0..15
    const float* base = outputs + (size_t)b * (NFEAT * 16);
    f32x4 acc = {};
    #pragma unroll
    for (int it = 0; it < 16; it++) {
        f32x4 v = *(const f32x4*)(base + (fo + it * 16) * 16 + j4 * 4);
        acc[0] += v[0]; acc[1] += v[1]; acc[2] += v[2]; acc[3] += v[3];
    }
    #pragma unroll
    for (int off = 4; off < 64; off <<= 1) {
        acc[0] += __shfl_xor(acc[0], off);
        acc[1] += __shfl_xor(acc[1], off);
        acc[2] += __shfl_xor(acc[2], off);
        acc[3] += __shfl_xor(acc[3], off);
    }
    if (lane < 4) {
        f32x4 bs = *(const f32x4*)(bias + lane * 4);
        acc[0] += bs[0]; acc[1] += bs[1]; acc[2] += bs[2]; acc[3] += bs[3];
        *(f32x4*)(logits + b * 16 + lane * 4) = acc;
    }
}

// ---------------------------------------------------------------------------
// main: persistent-f blocks, 256 thr = 4 waves (wo x wb = 2x2), BT=128.
// R8 phase structure (measured best), but L0/L1/L2 use 32x32x16 MFMA:
// halves MFMA instruction count (116->56 per wave-iter) at ~13% better
// per-FLOP rate.  L3 stays 16x16x32 (W3 has 16 rows).
// 32x32 C/D layout: col=lane&31, row=(reg&3)+8*(reg>>2)+4*(lane>>5).
// A/B frag: row=lane&31, k=(lane>>5)*8+j.
// XOR-swizzled LDS, 4 barriers/iter, weights persistent, biases streamed.
// ---------------------------------------------------------------------------
__global__ __launch_bounds__(256, 2) void nam_main(
    const u16* __restrict__ x_t, const u16* __restrict__ w0g,
    const u16* __restrict__ w1g, const u16* __restrict__ w2g, const u16* __restrict__ w3g,
    const float* __restrict__ b_in, const float* __restrict__ b_h0, const float* __restrict__ b_h1,
    float* __restrict__ outputs)
{
    __shared__ u16 hA[BT * 128];   // h0: 128 rows x 256B, later h2 (cols 0..127B)
    __shared__ u16 hB[BT * 128];   // h1: 128 rows x 256B

    const int bid   = blockIdx.x;
    const int f     = (bid & 7) * 32 + ((bid >> 3) & 31);  // XCD-contiguous features
    const int chunk = bid >> 8;                            // 0..7
    const int t  = threadIdx.x;
    const int w  = t >> 6;          // 0..3
    const int wo = w >> 1;          // o-half
    const int wb = w & 1;           // b-half
    const int lane = t & 63;
    const int lo  = lane & 15;      // 16x16 indices (L3)
    const int hi  = lane >> 4;
    const int l31 = lane & 31;      // 32x32 indices (L0/L1/L2)
    const int l5  = lane >> 5;      // 0..1

    // ---- persistent per-feature state ----
    bf16x8 a0f[2];                  // L0 A-frags {w0, bf16(b_in)} @ k=0,1
    #pragma unroll
    for (int mo = 0; mo < 2; mo++) {
        const int o = f * 128 + wo * 64 + mo * 32 + l31;
        float bi = b_in[o];
        u32 pk = (u32)w0g[o] | (cvtpk(bi, bi) << 16);
        a0f[mo] = frag_word0(l5 == 0 ? pk : 0u);
    }
    bf16x8 w1f[2][8];   // o = wo*64 + mo*32 + l31, k = ks*16 + l5*8
    {
        const u16* base = w1g + ((size_t)(f * 128 + wo * 64 + l31)) * 128 + l5 * 8;
        #pragma unroll
        for (int mo = 0; mo < 2; mo++)
            #pragma unroll
            for (int ks = 0; ks < 8; ks++)
                w1f[mo][ks] = *(const bf16x8*)(base + mo * 4096 + ks * 16);
    }
    bf16x8 w2f[8];      // o = wo*32 + l31, k = ks*16 + l5*8
    {
        const u16* base = w2g + ((size_t)(f * 64 + wo * 32 + l31)) * 128 + l5 * 8;
        #pragma unroll
        for (int ks = 0; ks < 8; ks++)
            w2f[ks] = *(const bf16x8*)(base + ks * 16);
    }
    bf16x8 w3f[2];      // 16x16: o = lo, k = ks*32 + hi*8
    {
        const u16* base = w3g + ((size_t)(f * 16 + lo)) * 64 + hi * 8;
        #pragma unroll
        for (int ks = 0; ks < 2; ks++)
            w3f[ks] = *(const bf16x8*)(base + ks * 32);
    }

    const u16* xbase = x_t + (size_t)f * NBATCH;

    // prime xw for first tile: x[b], b = wb*64 + n*32 + l31
    u32 xw[2];
    {
        const int bt0 = chunk * ITERS;
        #pragma unroll
        for (int n = 0; n < 2; n++)
            xw[n] = (u32)xbase[bt0 * BT + wb * 64 + n * 32 + l31];
    }

    for (int it = 0; it < ITERS; it++) {
        const int bt = chunk * ITERS + it;

        __syncthreads();   // prev iter's L3 reads of hA complete

        // ---------- layer 0 (rank-2, 32x32x16): h0[o][b] = relu(w0*x + b_in)
        {
            bf16x8 bm[2];
            #pragma unroll
            for (int n = 0; n < 2; n++)
                bm[n] = frag_word0(l5 == 0 ? (xw[n] | 0x3F800000u) : 0u);
            #pragma unroll
            for (int mo = 0; mo < 2; mo++) {
                #pragma unroll
                for (int n = 0; n < 2; n++) {
                    f32x16 d = mfma32(a0f[mo], bm[n], f32x16{});
                    const int b = wb * 64 + n * 32 + l31;
                    #pragma unroll
                    for (int q = 0; q < 4; q++) {
                        const int col2 = (wo * 64 + mo * 32 + q * 8 + l5 * 4) * 2;
                        u32 p0 = cvtpk(fmaxf(0.f, d[q * 4 + 0]), fmaxf(0.f, d[q * 4 + 1]));
                        u32 p1 = cvtpk(fmaxf(0.f, d[q * 4 + 2]), fmaxf(0.f, d[q * 4 + 3]));
                        *(uint2*)swz((char*)hA, b, col2) = make_uint2(p0, p1);
                    }
                }
            }
        }
        __syncthreads();

        // ---------- layer 1 (32x32x16): h1 = relu(W1 . h0^T + b_h0) ---------
        {
            // prefetch next tile's x under the MFMA phase
            if (it + 1 < ITERS) {
                #pragma unroll
                for (int n = 0; n < 2; n++)
                    xw[n] = (u32)xbase[(bt + 1) * BT + wb * 64 + n * 32 + l31];
            }
            f32x16 acc[2][2] = {};
            #pragma unroll
            for (int ks = 0; ks < 8; ks++) {
                bf16x8 bm[2];
                #pragma unroll
                for (int n = 0; n < 2; n++) {
                    const int b = wb * 64 + n * 32 + l31;
                    bm[n] = *(const bf16x8*)swz((const char*)hA, b, ks * 32 + l5 * 16);
                }
                __builtin_amdgcn_s_setprio(1);
                #pragma unroll
                for (int mo = 0; mo < 2; mo++)
                    #pragma unroll
                    for (int n = 0; n < 2; n++)
                        acc[mo][n] = mfma32(w1f[mo][ks], bm[n], acc[mo][n]);
                __builtin_amdgcn_s_setprio(0);
            }
            #pragma unroll
            for (int mo = 0; mo < 2; mo++) {
                #pragma unroll
                for (int q = 0; q < 4; q++) {
                    const int o = wo * 64 + mo * 32 + q * 8 + l5 * 4;
                    f32x4 bs = *(const f32x4*)(b_h0 + f * 128 + o);
                    #pragma unroll
                    for (int n = 0; n < 2; n++) {
                        const int b = wb * 64 + n * 32 + l31;
                        float s0 = acc[mo][n][q * 4 + 0] + bs[0];
                        float s1 = acc[mo][n][q * 4 + 1] + bs[1];
                        float s2 = acc[mo][n][q * 4 + 2] + bs[2];
                        float s3 = acc[mo][n][q * 4 + 3] + bs[3];
                        u32 p0 = cvtpk(fmaxf(s0, 0.f), fmaxf(s1, 0.f));
                        u32 p1 = cvtpk(fmaxf(s2, 0.f), fmaxf(s3, 0.f));
                        *(uint2*)swz((char*)hB, b, o * 2) = make_uint2(p0, p1);
                    }
                }
            }
        }
        __syncthreads();

        // ---------- layer 2 (32x32x16): h2 = relu(W2 . h1^T + b_h1) ---------
        // h2 -> hA rows (cols 0..127B of 256B rows)
        {
            f32x16 acc[2] = {};
            #pragma unroll
            for (int ks = 0; ks < 8; ks++) {
                bf16x8 bm[2];
                #pragma unroll
                for (int n = 0; n < 2; n++) {
                    const int b = wb * 64 + n * 32 + l31;
                    bm[n] = *(const bf16x8*)swz((const char*)hB, b, ks * 32 + l5 * 16);
                }
                __builtin_amdgcn_s_setprio(1);
                #pragma unroll
                for (int n = 0; n < 2; n++)
                    acc[n] = mfma32(w2f[ks], bm[n], acc[n]);
                __builtin_amdgcn_s_setprio(0);
            }
            #pragma unroll
            for (int q = 0; q < 4; q++) {
                const int o = wo * 32 + q * 8 + l5 * 4;
                f32x4 bs = *(const f32x4*)(b_h1 + f * 64 + o);
                #pragma unroll
                for (int n = 0; n < 2; n++) {
                    const int b = wb * 64 + n * 32 + l31;
                    float s0 = acc[n][q * 4 + 0] + bs[0];
                    float s1 = acc[n][q * 4 + 1] + bs[1];
                    float s2 = acc[n][q * 4 + 2] + bs[2];
                    float s3 = acc[n][q * 4 + 3] + bs[3];
                    u32 p0 = cvtpk(fmaxf(s0, 0.f), fmaxf(s1, 0.f));
                    u32 p1 = cvtpk(fmaxf(s2, 0.f), fmaxf(s3, 0.f));
                    *(uint2*)swz((char*)hA, b, o * 2) = make_uint2(p0, p1);
                }
            }
        }
        __syncthreads();

        // ---------- layer 3 (16x16x32): out = W3 (16x64) . h2^T -------------
        // 4 waves split b 4-ways: b = w*32 + n*16 + lo, n 0..1
        {
            f32x4 acc[2] = {};
            #pragma unroll
            for (int ks = 0; ks < 2; ks++) {
                #pragma unroll
                for (int n = 0; n < 2; n++) {
                    const int b = w * 32 + n * 16 + lo;
                    bf16x8 bm = *(const bf16x8*)swz((const char*)hA, b, ks * 64 + hi * 16);
                    acc[n] = mfma16(w3f[ks], bm, acc[n]);
                }
            }
            #pragma unroll
            for (int n = 0; n < 2; n++) {
                const int gb = bt * BT + w * 32 + n * 16 + lo;   // global batch row
                float* op = outputs + ((size_t)gb * NFEAT + f) * 16 + hi * 4;
                *(f32x4*)op = acc[n];
            }
        }
    }
}

// ---------------------------------------------------------------------------
extern "C" void kernel_launch(void* const* d_in, const int* in_sizes, int n_in,
                              void* d_out, int out_size, void* d_ws, size_t ws_size,
                              hipStream_t stream) {
    const float* tab   = (const float*)d_in[0];
    const float* v_in  = (const float*)d_in[1];
    const float* g_in  = (const float*)d_in[2];
    const float* b_in  = (const float*)d_in[3];
    const float* v_h0  = (const float*)d_in[4];
    const float* g_h0  = (const float*)d_in[5];
    const float* b_h0  = (const float*)d_in[6];
    const float* v_h1  = (const float*)d_in[7];
    const float* g_h1  = (const float*)d_in[8];
    const float* b_h1  = (const float*)d_in[9];
    const float* v_out = (const float*)d_in[10];
    const float* g_out = (const float*)d_in[11];
    const float* bias  = (const float*)d_in[12];

    char* ws = (char*)d_ws;
    u16* w0  = (u16*)(ws);                         //  32768 * 2
    u16* w1  = (u16*)(ws + 65536);                 // 4194304 * 2
    u16* w2  = (u16*)(ws + 65536 + 8388608);       // 2097152 * 2
    u16* w3  = (u16*)(ws + 12648448);              //  262144 * 2
    u16* x_t = (u16*)(ws + 13172736);              // 2097152 * 2  (end ~17.4MB)

    float* logits  = (float*)d_out;
    float* outputs = (float*)d_out + (size_t)NBATCH * 16;

    hipLaunchKernelGGL(prep_w0,   dim3(128),   dim3(256), 0, stream, v_in, g_in, w0);
    hipLaunchKernelGGL(prep_norm, dim3(13312), dim3(256), 0, stream,
                       v_h0, g_h0, v_h1, g_h1, v_out, g_out, w1, w2, w3);
    hipLaunchKernelGGL(prep_x,    dim3(512),   dim3(256), 0, stream, tab, x_t);
    hipLaunchKernelGGL(nam_main,  dim3(NFEAT * NBT / ITERS), dim3(256), 0, stream,
                       x_t, w0, w1, w2, w3, b_in, b_h0, b_h1, outputs);
    hipLaunchKernelGGL(reduce_logits, dim3(NBATCH / 4), dim3(256), 0, stream,
                       outputs, bias, logits);
}